// Round 1
// baseline (1121.006 us; speedup 1.0000x reference)
//
#include <hip/hip_runtime.h>
#include <hip/hip_bf16.h>

// Problem constants (from reference)
constexpr int N_NODES = 100000;
constexpr int N_EDGES = 1000000;
constexpr int D_NODE  = 64;
constexpr int D_EDGE  = 32;
constexpr int D_GLOB  = 32;
constexpr int OUT_DIM = 64;
constexpr int K1 = 2*D_NODE + D_EDGE + D_GLOB; // 192
constexpr int K2 = D_NODE + OUT_DIM + D_GLOB;  // 160

// ---------------------------------------------------------------------------
// Edge kernel: msg = relu([x[dst], x[src], edge_attr, u[batch[dst]]] @ W1 + b1)
// then atomicAdd into agg[dst] (agg lives in d_out, pre-zeroed).
// Layout: lane = output channel j (0..63); each wave register-blocks 8 edges.
// W1 staged in LDS once per block; 32-edge feature tile gathered per iter.
// ---------------------------------------------------------------------------
__global__ __launch_bounds__(256) void edge_kernel(
    const float* __restrict__ x, const int* __restrict__ ei,
    const float* __restrict__ ea, const float* __restrict__ u,
    const int* __restrict__ batch, const float* __restrict__ W1,
    const float* __restrict__ b1, float* __restrict__ agg)
{
    __shared__ float W1s[K1 * 64];        // 49152 B
    __shared__ float feats[32 * K1];      // 24576 B  (32 edges x 192)
    __shared__ int s_dst[32];
    __shared__ int s_src[32];
    __shared__ int s_b[32];

    const int tid  = threadIdx.x;
    const int lane = tid & 63;
    const int wv   = tid >> 6;

    // Stage W1 into LDS (float4, coalesced)
    {
        const float4* W14  = (const float4*)W1;
        float4*       W1s4 = (float4*)W1s;
        for (int i = tid; i < K1 * 64 / 4; i += 256) W1s4[i] = W14[i];
    }
    const float b1r = b1[lane];

    const float4* x4  = (const float4*)x;   // row = 16 float4
    const float4* ea4 = (const float4*)ea;  // row = 8 float4
    const float4* u4  = (const float4*)u;   // row = 8 float4
    float4* feats4 = (float4*)feats;        // [32][48]

    const int ntiles = N_EDGES / 32;        // 31250, exact
    for (int tile = blockIdx.x; tile < ntiles; tile += gridDim.x) {
        __syncthreads();  // previous iter's compute/epilogue done reading feats/s_dst
        if (tid < 32) {
            int e = tile * 32 + tid;
            int d = ei[N_EDGES + e];        // dst = edge_index[1]
            s_dst[tid] = d;
            s_src[tid] = ei[e];             // src = edge_index[0]
            s_b[tid]   = batch[d];
        }
        __syncthreads();

        // Cooperative gather: 32 edges x 48 float4 (= 192 floats) each
        for (int q = tid; q < 32 * 48; q += 256) {
            int el = q / 48;
            int c  = q - el * 48;
            int e  = tile * 32 + el;
            float4 v;
            if (c < 16)      v = x4[s_dst[el] * 16 + c];          // x[dst]
            else if (c < 32) v = x4[s_src[el] * 16 + (c - 16)];   // x[src]
            else if (c < 40) v = ea4[e * 8 + (c - 32)];           // edge_attr
            else             v = u4[s_b[el] * 8 + (c - 40)];      // u[batch[dst]]
            feats4[el * 48 + c] = v;
        }
        __syncthreads();

        // Compute: wave wv owns edges [wv*8, wv*8+8); lane = output channel
        float acc[8];
        #pragma unroll
        for (int e = 0; e < 8; ++e) acc[e] = 0.f;

        #pragma unroll 4
        for (int k = 0; k < K1; k += 4) {
            float w0 = W1s[(k + 0) * 64 + lane];
            float w1 = W1s[(k + 1) * 64 + lane];
            float w2 = W1s[(k + 2) * 64 + lane];
            float w3 = W1s[(k + 3) * 64 + lane];
            #pragma unroll
            for (int e = 0; e < 8; ++e) {
                float4 f = feats4[(wv * 8 + e) * 48 + (k >> 2)]; // broadcast read
                acc[e] += f.x * w0 + f.y * w1 + f.z * w2 + f.w * w3;
            }
        }

        #pragma unroll
        for (int e = 0; e < 8; ++e) {
            float v = acc[e] + b1r;
            v = v > 0.f ? v : 0.f;
            atomicAdd(&agg[s_dst[wv * 8 + e] * 64 + lane], v);   // coalesced
        }
    }
}

// ---------------------------------------------------------------------------
// Node kernel: out = relu([x, agg, u[batch]] @ W2 + b2)
// agg is read from `out` (in-place, row-exclusive per tile).
// ---------------------------------------------------------------------------
__global__ __launch_bounds__(256) void node_kernel(
    const float* __restrict__ x, const float* __restrict__ u,
    const int* __restrict__ batch, const float* __restrict__ W2,
    const float* __restrict__ b2, float* __restrict__ out)
{
    __shared__ float W2s[K2 * 64];        // 40960 B
    __shared__ float feats[32 * K2];      // 20480 B
    __shared__ int s_b[32];

    const int tid  = threadIdx.x;
    const int lane = tid & 63;
    const int wv   = tid >> 6;

    {
        const float4* W24  = (const float4*)W2;
        float4*       W2s4 = (float4*)W2s;
        for (int i = tid; i < K2 * 64 / 4; i += 256) W2s4[i] = W24[i];
    }
    const float b2r = b2[lane];

    const float4* x4 = (const float4*)x;
    const float4* u4 = (const float4*)u;
    const float4* o4 = (const float4*)out;
    float4* feats4 = (float4*)feats;      // [32][40]

    const int ntiles = N_NODES / 32;      // 3125, exact
    for (int tile = blockIdx.x; tile < ntiles; tile += gridDim.x) {
        __syncthreads();
        if (tid < 32) {
            int n = tile * 32 + tid;
            s_b[tid] = batch[n];
        }
        __syncthreads();

        // Gather: 32 nodes x 40 float4 (x:16 | agg:16 | u:8)
        for (int q = tid; q < 32 * 40; q += 256) {
            int nl = q / 40;
            int c  = q - nl * 40;
            int n  = tile * 32 + nl;
            float4 v;
            if (c < 16)      v = x4[n * 16 + c];                  // x
            else if (c < 32) v = o4[n * 16 + (c - 16)];           // agg (in d_out)
            else             v = u4[s_b[nl] * 8 + (c - 32)];      // u[batch]
            feats4[nl * 40 + c] = v;
        }
        __syncthreads();

        float acc[8];
        #pragma unroll
        for (int e = 0; e < 8; ++e) acc[e] = 0.f;

        #pragma unroll 4
        for (int k = 0; k < K2; k += 4) {
            float w0 = W2s[(k + 0) * 64 + lane];
            float w1 = W2s[(k + 1) * 64 + lane];
            float w2 = W2s[(k + 2) * 64 + lane];
            float w3 = W2s[(k + 3) * 64 + lane];
            #pragma unroll
            for (int e = 0; e < 8; ++e) {
                float4 f = feats4[(wv * 8 + e) * 40 + (k >> 2)];
                acc[e] += f.x * w0 + f.y * w1 + f.z * w2 + f.w * w3;
            }
        }

        #pragma unroll
        for (int e = 0; e < 8; ++e) {
            int n = tile * 32 + wv * 8 + e;
            float v = acc[e] + b2r;
            out[n * 64 + lane] = v > 0.f ? v : 0.f;
        }
    }
}

extern "C" void kernel_launch(void* const* d_in, const int* in_sizes, int n_in,
                              void* d_out, int out_size, void* d_ws, size_t ws_size,
                              hipStream_t stream) {
    const float* x     = (const float*)d_in[0];
    const int*   ei    = (const int*)d_in[1];
    const float* ea    = (const float*)d_in[2];
    const float* u     = (const float*)d_in[3];
    const int*   batch = (const int*)d_in[4];
    const float* W1    = (const float*)d_in[5];
    const float* b1    = (const float*)d_in[6];
    const float* W2    = (const float*)d_in[7];
    const float* b2    = (const float*)d_in[8];
    float* out = (float*)d_out;

    // agg accumulates in d_out; zero it first (stream-ordered, capture-safe)
    hipMemsetAsync(out, 0, (size_t)out_size * sizeof(float), stream);

    edge_kernel<<<512, 256, 0, stream>>>(x, ei, ea, u, batch, W1, b1, out);
    node_kernel<<<512, 256, 0, stream>>>(x, u, batch, W2, b2, out);
}

// Round 2
// 544.544 us; speedup vs baseline: 2.0586x; 2.0586x over previous
//
#include <hip/hip_runtime.h>
#include <hip/hip_bf16.h>

// Problem constants (from reference)
constexpr int N_NODES = 100000;
constexpr int N_EDGES = 1000000;
constexpr int D_NODE  = 64;
constexpr int D_EDGE  = 32;
constexpr int D_GLOB  = 32;
constexpr int OUT_DIM = 64;
constexpr int K1 = 2*D_NODE + D_EDGE + D_GLOB; // 192
constexpr int K2 = D_NODE + OUT_DIM + D_GLOB;  // 160

typedef __bf16 bf16x8 __attribute__((ext_vector_type(8)));
typedef float floatx4 __attribute__((ext_vector_type(4)));
typedef unsigned short ushort8 __attribute__((ext_vector_type(8)));

// feats row stride in bf16 elems: 200*2=400 B rows (16B-aligned); dword bank
// base per row = 100 % 32 = 4 -> A-frag reads are 2-way bank aliased (free).
constexpr int FS = 200;

// ---------------------------------------------------------------------------
// Edge kernel (MFMA): msg = relu([x[dst],x[src],ea,u[batch[dst]]] @ W1 + b1)
// atomicAdd into agg[dst] (agg lives in d_out, pre-zeroed).
// 64 edges per tile; wave wv owns edges [wv*16, wv*16+16) x all 64 channels.
// W1 fragments live in registers (24 x bf16x8); LDS buffer is shared between
// the one-time W1 transpose and the per-tile feature staging.
// ---------------------------------------------------------------------------
__global__ __launch_bounds__(256, 3) void edge_kernel(
    const float* __restrict__ x, const int* __restrict__ ei,
    const float* __restrict__ ea, const float* __restrict__ u,
    const int* __restrict__ batch, const float* __restrict__ W1,
    const float* __restrict__ b1, float* __restrict__ agg)
{
    __shared__ __align__(16) unsigned short smem[64 * FS]; // 25600 B
    __shared__ int s_dst[64];
    __shared__ int s_src[64];
    __shared__ int s_b[64];

    const int tid  = threadIdx.x;
    const int lane = tid & 63;
    const int wv   = tid >> 6;
    const int quad = lane >> 4;
    const int nl   = lane & 15;

    // ---- one-time: stage W1 (fp32 [k=192][n=64]) -> smem = W1t bf16 [n][k]
    for (int i = tid; i < K1 * 64; i += 256) {
        int k = i >> 6, n = i & 63;
        __hip_bfloat16 h = __float2bfloat16(W1[i]);
        smem[n * FS + k] = *(unsigned short*)&h;
    }
    __syncthreads();

    // ---- preload B fragments: Bf[t][s]; element j = W1[s*32+quad*8+j][t*16+nl]
    bf16x8 Bf[4][6];
    #pragma unroll
    for (int t = 0; t < 4; ++t)
        #pragma unroll
        for (int s = 0; s < 6; ++s)
            Bf[t][s] = __builtin_bit_cast(bf16x8,
                *(const ushort8*)&smem[(t*16 + nl) * FS + s*32 + quad*8]);

    float b1v[4];
    #pragma unroll
    for (int t = 0; t < 4; ++t) b1v[t] = b1[t*16 + nl];

    const float4* x4  = (const float4*)x;   // row = 16 float4
    const float4* ea4 = (const float4*)ea;  // row = 8 float4
    const float4* u4  = (const float4*)u;   // row = 8 float4

    const int ntiles = N_EDGES / 64;        // 15625, exact
    for (int tile = blockIdx.x; tile < ntiles; tile += gridDim.x) {
        __syncthreads();  // prior compute (and init B-frag reads) done with smem
        if (tid < 64) {
            int e = tile * 64 + tid;
            int d = ei[N_EDGES + e];        // dst = edge_index[1]
            s_dst[tid] = d;
            s_src[tid] = ei[e];             // src = edge_index[0]
            s_b[tid]   = batch[d];
        }
        __syncthreads();

        // gather+convert: 64 edges x 48 float4-chunks -> bf16x4 chunks in LDS
        for (int q = tid; q < 64 * 48; q += 256) {
            int el = q / 48;
            int c  = q - el * 48;
            float4 v;
            if (c < 16)      v = x4[s_dst[el] * 16 + c];              // x[dst]
            else if (c < 32) v = x4[s_src[el] * 16 + (c - 16)];       // x[src]
            else if (c < 40) v = ea4[(tile*64 + el) * 8 + (c - 32)];  // edge_attr
            else             v = u4[s_b[el] * 8 + (c - 40)];          // u[batch[dst]]
            __hip_bfloat162 p0 = __float22bfloat162_rn(float2{v.x, v.y});
            __hip_bfloat162 p1 = __float22bfloat162_rn(float2{v.z, v.w});
            uint2 pk;
            pk.x = *(unsigned int*)&p0;
            pk.y = *(unsigned int*)&p1;
            *(uint2*)&smem[el * FS + c * 4] = pk;
        }
        __syncthreads();

        // compute: A rows = this wave's 16 edges; k-steps of 32; 4 n-tiles
        floatx4 acc[4] = {floatx4{0,0,0,0}, floatx4{0,0,0,0},
                          floatx4{0,0,0,0}, floatx4{0,0,0,0}};
        #pragma unroll
        for (int s = 0; s < 6; ++s) {
            bf16x8 a = __builtin_bit_cast(bf16x8,
                *(const ushort8*)&smem[(wv*16 + nl) * FS + s*32 + quad*8]);
            #pragma unroll
            for (int t = 0; t < 4; ++t)
                acc[t] = __builtin_amdgcn_mfma_f32_16x16x32_bf16(a, Bf[t][s], acc[t], 0, 0, 0);
        }

        // epilogue: C layout col = nl, row = quad*4 + r; bias + relu + atomic
        #pragma unroll
        for (int r = 0; r < 4; ++r) {
            int e = wv*16 + quad*4 + r;
            float* base = agg + s_dst[e] * 64 + nl;
            #pragma unroll
            for (int t = 0; t < 4; ++t) {
                float vv = acc[t][r] + b1v[t];
                vv = vv > 0.f ? vv : 0.f;
                atomicAdd(base + t*16, vv);
            }
        }
    }
}

// ---------------------------------------------------------------------------
// Node kernel: out = relu([x, agg, u[batch]] @ W2 + b2)  (fp32, unchanged)
// agg is read from `out` (in-place, row-exclusive per tile).
// ---------------------------------------------------------------------------
__global__ __launch_bounds__(256) void node_kernel(
    const float* __restrict__ x, const float* __restrict__ u,
    const int* __restrict__ batch, const float* __restrict__ W2,
    const float* __restrict__ b2, float* __restrict__ out)
{
    __shared__ float W2s[K2 * 64];        // 40960 B
    __shared__ float feats[32 * K2];      // 20480 B
    __shared__ int s_b[32];

    const int tid  = threadIdx.x;
    const int lane = tid & 63;
    const int wv   = tid >> 6;

    {
        const float4* W24  = (const float4*)W2;
        float4*       W2s4 = (float4*)W2s;
        for (int i = tid; i < K2 * 64 / 4; i += 256) W2s4[i] = W24[i];
    }
    const float b2r = b2[lane];

    const float4* x4 = (const float4*)x;
    const float4* u4 = (const float4*)u;
    const float4* o4 = (const float4*)out;
    float4* feats4 = (float4*)feats;      // [32][40]

    const int ntiles = N_NODES / 32;      // 3125, exact
    for (int tile = blockIdx.x; tile < ntiles; tile += gridDim.x) {
        __syncthreads();
        if (tid < 32) {
            int n = tile * 32 + tid;
            s_b[tid] = batch[n];
        }
        __syncthreads();

        for (int q = tid; q < 32 * 40; q += 256) {
            int nl2 = q / 40;
            int c  = q - nl2 * 40;
            int n  = tile * 32 + nl2;
            float4 v;
            if (c < 16)      v = x4[n * 16 + c];                  // x
            else if (c < 32) v = o4[n * 16 + (c - 16)];           // agg (in d_out)
            else             v = u4[s_b[nl2] * 8 + (c - 32)];     // u[batch]
            feats4[nl2 * 40 + c] = v;
        }
        __syncthreads();

        float acc[8];
        #pragma unroll
        for (int e = 0; e < 8; ++e) acc[e] = 0.f;

        #pragma unroll 4
        for (int k = 0; k < K2; k += 4) {
            float w0 = W2s[(k + 0) * 64 + lane];
            float w1 = W2s[(k + 1) * 64 + lane];
            float w2 = W2s[(k + 2) * 64 + lane];
            float w3 = W2s[(k + 3) * 64 + lane];
            #pragma unroll
            for (int e = 0; e < 8; ++e) {
                float4 f = feats4[(wv * 8 + e) * 40 + (k >> 2)];
                acc[e] += f.x * w0 + f.y * w1 + f.z * w2 + f.w * w3;
            }
        }

        #pragma unroll
        for (int e = 0; e < 8; ++e) {
            int n = tile * 32 + wv * 8 + e;
            float v = acc[e] + b2r;
            out[n * 64 + lane] = v > 0.f ? v : 0.f;
        }
    }
}

extern "C" void kernel_launch(void* const* d_in, const int* in_sizes, int n_in,
                              void* d_out, int out_size, void* d_ws, size_t ws_size,
                              hipStream_t stream) {
    const float* x     = (const float*)d_in[0];
    const int*   ei    = (const int*)d_in[1];
    const float* ea    = (const float*)d_in[2];
    const float* u     = (const float*)d_in[3];
    const int*   batch = (const int*)d_in[4];
    const float* W1    = (const float*)d_in[5];
    const float* b1    = (const float*)d_in[6];
    const float* W2    = (const float*)d_in[7];
    const float* b2    = (const float*)d_in[8];
    float* out = (float*)d_out;

    // agg accumulates in d_out; zero it first (stream-ordered, capture-safe)
    hipMemsetAsync(out, 0, (size_t)out_size * sizeof(float), stream);

    edge_kernel<<<768, 256, 0, stream>>>(x, ei, ea, u, batch, W1, b1, out);
    node_kernel<<<512, 256, 0, stream>>>(x, u, batch, W2, b2, out);
}

// Round 3
// 483.260 us; speedup vs baseline: 2.3197x; 1.1268x over previous
//
#include <hip/hip_runtime.h>
#include <hip/hip_bf16.h>

// Problem constants (from reference)
constexpr int N_NODES = 100000;
constexpr int N_EDGES = 1000000;
constexpr int D_NODE  = 64;
constexpr int D_EDGE  = 32;
constexpr int D_GLOB  = 32;
constexpr int OUT_DIM = 64;
constexpr int K1 = 2*D_NODE + D_EDGE + D_GLOB; // 192
constexpr int K2 = D_NODE + OUT_DIM + D_GLOB;  // 160

typedef __bf16 bf16x8 __attribute__((ext_vector_type(8)));
typedef unsigned short ushort8_t __attribute__((ext_vector_type(8)));
typedef float floatx16 __attribute__((ext_vector_type(16)));

// LDS feature-tile row stride (bf16 elems): 400 B rows, 16B-aligned;
// dword bank base per row = 100*row % 32 = 4*row -> A-frag b128 reads are
// 2-way bank aliased (free, per m136).
constexpr int FS = 200;

// d_ws layout (bytes), all 16B-aligned:
//   [0,     24576)  W1t bf16 [64][192]   (transposed: [n][k])
//   [24576, 45056)  W2t bf16 [64][160]
//   [45056, 46080)  ub  bf16 [16][32]
//   [46080, ...  )  xb  bf16 [100000][64]  (12.8 MB)
constexpr size_t WS_W1T = 0;
constexpr size_t WS_W2T = 24576;
constexpr size_t WS_UB  = 45056;
constexpr size_t WS_XB  = 46080;

__device__ inline unsigned pack_bf2(float a, float b) {
    __hip_bfloat162 h = __float22bfloat162_rn(float2{a, b});
    return *(unsigned*)&h;
}

// ---------------------------------------------------------------------------
// Prep: bf16-convert x, u; bf16+transpose W1, W2 into d_ws. Runs every launch
// (harness re-poisons d_ws).
// ---------------------------------------------------------------------------
__global__ __launch_bounds__(256) void prep_kernel(
    const float* __restrict__ x, const float* __restrict__ u,
    const float* __restrict__ W1, const float* __restrict__ W2,
    unsigned short* __restrict__ ws_w1t, unsigned short* __restrict__ ws_w2t,
    unsigned short* __restrict__ ws_ub, unsigned short* __restrict__ ws_xb)
{
    const int t = blockIdx.x * 256 + threadIdx.x;
    const int stride = gridDim.x * 256;
    const float4* x4 = (const float4*)x;
    for (int i = t; i < N_NODES * 16; i += stride) {       // x: 1.6M float4
        float4 v = x4[i];
        uint2 pk;
        pk.x = pack_bf2(v.x, v.y);
        pk.y = pack_bf2(v.z, v.w);
        *(uint2*)&ws_xb[i * 4] = pk;
    }
    for (int i = t; i < K1 * 64; i += stride) {            // W1 [k][n] -> [n][k]
        int k = i >> 6, n = i & 63;
        __hip_bfloat16 h = __float2bfloat16(W1[i]);
        ws_w1t[n * K1 + k] = *(unsigned short*)&h;
    }
    for (int i = t; i < K2 * 64; i += stride) {            // W2 [k][n] -> [n][k]
        int k = i >> 6, n = i & 63;
        __hip_bfloat16 h = __float2bfloat16(W2[i]);
        ws_w2t[n * K2 + k] = *(unsigned short*)&h;
    }
    for (int i = t; i < 16 * D_GLOB; i += stride) {        // u
        __hip_bfloat16 h = __float2bfloat16(u[i]);
        ws_ub[i] = *(unsigned short*)&h;
    }
}

// ---------------------------------------------------------------------------
// Edge kernel (32x32x16 MFMA): msg = relu([x[dst],x[src],ea,u[b[dst]]]@W1+b1)
// atomicAdd into agg[dst] (= d_out, pre-zeroed). One 64-edge tile per block.
// Wave wv: edge-half eh=wv>>1 (32 edges), channel-half nh=wv&1 (32 ch).
// B frags (12 x bf16x8 = 48 VGPR) loaded straight from L2-hot W1t.
// ---------------------------------------------------------------------------
__global__ __launch_bounds__(256, 4) void edge_kernel(
    const unsigned short* __restrict__ xb, const int* __restrict__ ei,
    const float* __restrict__ ea, const unsigned short* __restrict__ ub,
    const int* __restrict__ batch, const unsigned short* __restrict__ W1t,
    const float* __restrict__ b1, float* __restrict__ agg)
{
    __shared__ __align__(16) unsigned short smem[64 * FS]; // 25600 B
    __shared__ int s_dst[64];
    __shared__ int s_src[64];
    __shared__ int s_b[64];

    const int tid  = threadIdx.x;
    const int lane = tid & 63;
    const int wv   = tid >> 6;
    const int tile = blockIdx.x;
    const int eh   = wv >> 1;
    const int nh   = wv & 1;
    const int col  = lane & 31;
    const int half = lane >> 5;

    if (tid < 64) {
        int e = tile * 64 + tid;
        int d = ei[N_EDGES + e];            // dst = edge_index[1]
        s_dst[tid] = d;
        s_src[tid] = ei[e];                 // src = edge_index[0]
        s_b[tid]   = batch[d];
    }

    // B fragments: B[k][n], n = nh*32+col, k = s*16 + half*8 + j
    bf16x8 Bf[12];
    #pragma unroll
    for (int s = 0; s < 12; ++s)
        Bf[s] = __builtin_bit_cast(bf16x8,
            *(const ushort8_t*)&W1t[(nh*32 + col) * K1 + s*16 + half*8]);
    const float b1v = b1[nh*32 + col];

    __syncthreads();

    // Gather: 64 edges x 24 16B-chunks of bf16 (x[dst]:8 | x[src]:8 | ea:4 | u:4)
    const float4* ea4 = (const float4*)ea;
    for (int q = tid; q < 64 * 24; q += 256) {
        int el = q / 24;
        int c  = q - el * 24;
        uint4 pk;
        if (c < 8)       pk = *(const uint4*)&xb[s_dst[el] * 64 + c * 8];
        else if (c < 16) pk = *(const uint4*)&xb[s_src[el] * 64 + (c - 8) * 8];
        else if (c < 20) {
            float4 v0 = ea4[(tile*64 + el) * 8 + (c - 16) * 2 + 0];
            float4 v1 = ea4[(tile*64 + el) * 8 + (c - 16) * 2 + 1];
            pk.x = pack_bf2(v0.x, v0.y); pk.y = pack_bf2(v0.z, v0.w);
            pk.z = pack_bf2(v1.x, v1.y); pk.w = pack_bf2(v1.z, v1.w);
        } else           pk = *(const uint4*)&ub[s_b[el] * 32 + (c - 20) * 8];
        *(uint4*)&smem[el * FS + c * 8] = pk;
    }
    __syncthreads();

    // Compute: A rows = eh*32 + (lane&31), k = s*16 + half*8 + j
    floatx16 acc = {0,0,0,0,0,0,0,0,0,0,0,0,0,0,0,0};
    #pragma unroll
    for (int s = 0; s < 12; ++s) {
        bf16x8 a = __builtin_bit_cast(bf16x8,
            *(const ushort8_t*)&smem[(eh*32 + col) * FS + s*16 + half*8]);
        acc = __builtin_amdgcn_mfma_f32_32x32x16_bf16(a, Bf[s], acc, 0, 0, 0);
    }

    // Epilogue: C layout col=lane&31, row=(r&3)+8*(r>>2)+4*half
    #pragma unroll
    for (int r = 0; r < 16; ++r) {
        int e = eh*32 + (r & 3) + 8*(r >> 2) + 4*half;
        float vv = acc[r] + b1v;
        vv = vv > 0.f ? vv : 0.f;
        atomicAdd(&agg[s_dst[e] * 64 + nh*32 + col], vv);
    }
}

// ---------------------------------------------------------------------------
// Node kernel (32x32x16 MFMA): out = relu([x, agg, u[batch]] @ W2 + b2)
// agg read fp32 from d_out, converted to bf16 in the gather; in-place,
// row-exclusive per block. One 64-node tile per block (tail guarded).
// ---------------------------------------------------------------------------
__global__ __launch_bounds__(256, 4) void node_kernel(
    const unsigned short* __restrict__ xb, const unsigned short* __restrict__ ub,
    const int* __restrict__ batch, const unsigned short* __restrict__ W2t,
    const float* __restrict__ b2, float* __restrict__ out)
{
    __shared__ __align__(16) unsigned short smem[64 * FS];
    __shared__ int s_b[64];

    const int tid  = threadIdx.x;
    const int lane = tid & 63;
    const int wv   = tid >> 6;
    const int base = blockIdx.x * 64;
    const int eh   = wv >> 1;
    const int nh   = wv & 1;
    const int col  = lane & 31;
    const int half = lane >> 5;

    if (tid < 64) {
        int n = base + tid;
        s_b[tid] = (n < N_NODES) ? batch[n] : 0;
    }

    bf16x8 Bf[10];
    #pragma unroll
    for (int s = 0; s < 10; ++s)
        Bf[s] = __builtin_bit_cast(bf16x8,
            *(const ushort8_t*)&W2t[(nh*32 + col) * K2 + s*16 + half*8]);
    const float b2v = b2[nh*32 + col];

    __syncthreads();

    // Gather: 64 nodes x 20 16B-chunks (x:8 | agg:8 | u:4)
    const float4* o4 = (const float4*)out;
    for (int q = tid; q < 64 * 20; q += 256) {
        int nl = q / 20;
        int c  = q - nl * 20;
        int n  = base + nl;
        uint4 pk;
        if (n >= N_NODES) pk = uint4{0, 0, 0, 0};
        else if (c < 8)   pk = *(const uint4*)&xb[n * 64 + c * 8];
        else if (c < 16) {
            float4 v0 = o4[n * 16 + (c - 8) * 2 + 0];
            float4 v1 = o4[n * 16 + (c - 8) * 2 + 1];
            pk.x = pack_bf2(v0.x, v0.y); pk.y = pack_bf2(v0.z, v0.w);
            pk.z = pack_bf2(v1.x, v1.y); pk.w = pack_bf2(v1.z, v1.w);
        } else            pk = *(const uint4*)&ub[s_b[nl] * 32 + (c - 16) * 8];
        *(uint4*)&smem[nl * FS + c * 8] = pk;
    }
    __syncthreads();

    floatx16 acc = {0,0,0,0,0,0,0,0,0,0,0,0,0,0,0,0};
    #pragma unroll
    for (int s = 0; s < 10; ++s) {
        bf16x8 a = __builtin_bit_cast(bf16x8,
            *(const ushort8_t*)&smem[(eh*32 + col) * FS + s*16 + half*8]);
        acc = __builtin_amdgcn_mfma_f32_32x32x16_bf16(a, Bf[s], acc, 0, 0, 0);
    }

    #pragma unroll
    for (int r = 0; r < 16; ++r) {
        int n = base + eh*32 + (r & 3) + 8*(r >> 2) + 4*half;
        if (n < N_NODES) {
            float vv = acc[r] + b2v;
            out[n * 64 + nh*32 + col] = vv > 0.f ? vv : 0.f;
        }
    }
}

extern "C" void kernel_launch(void* const* d_in, const int* in_sizes, int n_in,
                              void* d_out, int out_size, void* d_ws, size_t ws_size,
                              hipStream_t stream) {
    const float* x     = (const float*)d_in[0];
    const int*   ei    = (const int*)d_in[1];
    const float* ea    = (const float*)d_in[2];
    const float* u     = (const float*)d_in[3];
    const int*   batch = (const int*)d_in[4];
    const float* W1    = (const float*)d_in[5];
    const float* b1    = (const float*)d_in[6];
    const float* W2    = (const float*)d_in[7];
    const float* b2    = (const float*)d_in[8];
    float* out = (float*)d_out;

    unsigned short* ws_w1t = (unsigned short*)((char*)d_ws + WS_W1T);
    unsigned short* ws_w2t = (unsigned short*)((char*)d_ws + WS_W2T);
    unsigned short* ws_ub  = (unsigned short*)((char*)d_ws + WS_UB);
    unsigned short* ws_xb  = (unsigned short*)((char*)d_ws + WS_XB);

    // agg accumulates in d_out; zero it first (stream-ordered, capture-safe)
    hipMemsetAsync(out, 0, (size_t)out_size * sizeof(float), stream);

    prep_kernel<<<2048, 256, 0, stream>>>(x, u, W1, W2, ws_w1t, ws_w2t, ws_ub, ws_xb);
    edge_kernel<<<N_EDGES / 64, 256, 0, stream>>>(ws_xb, ei, ea, ws_ub, batch, ws_w1t, b1, out);
    node_kernel<<<(N_NODES + 63) / 64, 256, 0, stream>>>(ws_xb, ws_ub, batch, ws_w2t, b2, out);
}